// Round 1
// baseline (24391.489 us; speedup 1.0000x reference)
//
#include <hip/hip_runtime.h>
#include <hip/hip_bf16.h>

#define T_STEPS 2048
#define BATCH   256
#define DIN     16
#define HIDDEN  256
#define KROW    296      // padded A row stride (bf16 elems): 256 h + 16 x + 16 zero + 8 pad
#define NT_ALL  65       // 64 gate tiles + 1 output tile
#define KSTEPS  9        // K = 288 = 9 * 32
#define BBLK    16       // batch rows per block
#define NBLK    16       // blocks

typedef __attribute__((ext_vector_type(8))) short bf16x8;
typedef __attribute__((ext_vector_type(4))) float f32x4;

__device__ __forceinline__ float fast_sigmoid(float x) {
    return __builtin_amdgcn_rcpf(1.f + __expf(-x));
}
__device__ __forceinline__ float fast_tanh(float x) {
    // 1 - 2/(1+e^{2x}); graceful at +-inf via rcp(inf)=0
    return 1.f - 2.f * __builtin_amdgcn_rcpf(1.f + __expf(2.f * x));
}

// Pack W into MFMA-B fragment order: Wp[((tt*9+kt)*64+lane)*8+e] = B[k][n]
// tiles tt<64: (jt=tt>>2, gate=tt&3) -> rows g = gate*256 + jt*16 + (lane&15)
// tile 64: rows 0..2 = W_uvw, 3..5 = W_pqr, rest zero (x-cols zero).
// k layout: [0,256) = W_hh k, [256,272) = W_ih, [272,288) = zero pad.
__global__ void pack_kernel(const float* __restrict__ W_ih, const float* __restrict__ W_hh,
                            const float* __restrict__ b_ih, const float* __restrict__ b_hh,
                            const float* __restrict__ W_uvw, const float* __restrict__ b_uvw,
                            const float* __restrict__ W_pqr, const float* __restrict__ b_pqr,
                            __hip_bfloat16* __restrict__ Wp, float* __restrict__ bias) {
    int idx = blockIdx.x * 256 + threadIdx.x;
    const int TOT = NT_ALL * KSTEPS * 64 * 8;
    if (idx < TOT) {
        int e   = idx & 7;
        int L   = (idx >> 3) & 63;
        int rem = idx >> 9;
        int kt  = rem % KSTEPS;
        int tt  = rem / KSTEPS;
        int n   = L & 15;
        int k   = kt * 32 + (L >> 4) * 8 + e;
        float v = 0.f;
        if (tt < 64) {
            int g = (tt & 3) * 256 + (tt >> 2) * 16 + n;
            if (k < 256)       v = W_hh[g * 256 + k];
            else if (k < 272)  v = W_ih[g * 16 + (k - 256)];
        } else if (k < 256) {
            if (n < 3)      v = W_uvw[n * 256 + k];
            else if (n < 6) v = W_pqr[(n - 3) * 256 + k];
        }
        Wp[idx] = __float2bfloat16(v);
    }
    if (idx < NT_ALL * 16) {
        int tt = idx >> 4, n = idx & 15;
        float bv = 0.f;
        if (tt < 64) {
            int g = (tt & 3) * 256 + (tt >> 2) * 16 + n;
            bv = b_ih[g] + b_hh[g];
        } else {
            if (n < 3)      bv = b_uvw[n];
            else if (n < 6) bv = b_pqr[n - 3];
        }
        bias[idx] = bv;
    }
}

// Persistent LSTM: 16 blocks x 512 threads (8 waves). Block bg owns batch rows
// [bg*16, bg*16+16). Wave w owns hidden j in [32w, 32w+32) = tiles 8w..8w+7
// (jt,gate interleaved: i,f,g,o for a jt are acc[4*pr+0..3], same lane&15 col).
// Wave 7 additionally computes the output tile (tile 64).
__global__ __launch_bounds__(512, 2) void lstm_kernel(
        const float* __restrict__ xs, const __hip_bfloat16* __restrict__ Wp,
        const float* __restrict__ bias, float* __restrict__ out) {
    __shared__ __hip_bfloat16 Abuf[2][BBLK][KROW];
    const int tid  = threadIdx.x;
    const int w    = tid >> 6;
    const int lane = tid & 63;
    const int bg   = blockIdx.x;
    const int tb   = w * 8;
    const int arow = lane & 15;
    const int akc  = lane >> 4;

    // zero the A panels (h_{-1}=0 and the zero-pad K columns)
    for (int i = tid; i < 2 * BBLK * KROW; i += 512)
        ((__hip_bfloat16*)Abuf)[i] = __float2bfloat16(0.f);
    // stage x_0
    if (tid < 256) {
        float x0 = xs[(bg * BBLK + (tid >> 4)) * DIN + (tid & 15)];
        Abuf[0][tid >> 4][256 + (tid & 15)] = __float2bfloat16(x0);
    }

    // per-tile bias (one f32 per lane per tile; broadcast over the 4 rows)
    float bs[9];
    #pragma unroll
    for (int i = 0; i < 8; ++i) bs[i] = bias[(tb + i) * 16 + arow];
    bs[8] = (w == 7) ? bias[64 * 16 + arow] : 0.f;

    // persistent W fragments for this wave's tile 0 (W is step-invariant)
    const bf16x8* Wf = (const bf16x8*)Wp;
    bf16x8 wp0[9];
    #pragma unroll
    for (int kt = 0; kt < KSTEPS; ++kt) wp0[kt] = Wf[(tb * KSTEPS + kt) * 64 + lane];

    float cst[8];
    #pragma unroll
    for (int i = 0; i < 8; ++i) cst[i] = 0.f;

    __syncthreads();

    for (int t = 0; t < T_STEPS; ++t) {
        const int p  = t & 1;
        const int pn = p ^ 1;

        f32x4 acc[9];
        #pragma unroll
        for (int i = 0; i < 9; ++i) acc[i] = (f32x4){bs[i], bs[i], bs[i], bs[i]};

        // prefetch x_{t+1} (hidden under MFMA phase)
        float xv = 0.f;
        if (tid < 256) {
            int tn = (t + 1 < T_STEPS) ? (t + 1) : t;
            xv = xs[((size_t)tn * BATCH + bg * BBLK + (tid >> 4)) * DIN + (tid & 15)];
        }

        // A fragments: lane reads A[lane&15][kt*32 + (lane>>4)*8 .. +8]
        bf16x8 af[9];
        const __hip_bfloat16* abase = &Abuf[p][arow][akc * 8];
        #pragma unroll
        for (int kt = 0; kt < KSTEPS; ++kt)
            af[kt] = *(const bf16x8*)(abase + kt * 32);

        // stream W tiles from L2 with 1-tile register double-buffer
        bf16x8 wreg[2][9];
        #pragma unroll
        for (int i = 0; i < 8; ++i) {
            if (i < 7) {
                #pragma unroll
                for (int kt = 0; kt < KSTEPS; ++kt)
                    wreg[(i + 1) & 1][kt] = Wf[((tb + i + 1) * KSTEPS + kt) * 64 + lane];
            } else if (w == 7) {
                #pragma unroll
                for (int kt = 0; kt < KSTEPS; ++kt)
                    wreg[0][kt] = Wf[(64 * KSTEPS + kt) * 64 + lane];
            }
            if (i == 0) {
                #pragma unroll
                for (int kt = 0; kt < KSTEPS; ++kt)
                    acc[0] = __builtin_amdgcn_mfma_f32_16x16x32_bf16(af[kt], wp0[kt], acc[0], 0, 0, 0);
            } else {
                #pragma unroll
                for (int kt = 0; kt < KSTEPS; ++kt)
                    acc[i] = __builtin_amdgcn_mfma_f32_16x16x32_bf16(af[kt], wreg[i & 1][kt], acc[i], 0, 0, 0);
            }
        }
        if (w == 7) {
            #pragma unroll
            for (int kt = 0; kt < KSTEPS; ++kt)
                acc[8] = __builtin_amdgcn_mfma_f32_16x16x32_bf16(af[kt], wreg[0][kt], acc[8], 0, 0, 0);
            // this pass used h_{t-1}: it is out[t-1]
            int n = lane & 15;
            if (t >= 1 && n < 6) {
                #pragma unroll
                for (int r = 0; r < 4; ++r) {
                    int b = akc * 4 + r;
                    out[(((size_t)(t - 1) * BATCH) + bg * BBLK + b) * 6 + n] = acc[8][r];
                }
            }
        }

        // epilogue: lane-local activations; c stays in registers
        #pragma unroll
        for (int pr = 0; pr < 2; ++pr) {
            #pragma unroll
            for (int r = 0; r < 4; ++r) {
                float iv = acc[pr * 4 + 0][r];
                float fv = acc[pr * 4 + 1][r];
                float gv = acc[pr * 4 + 2][r];
                float ov = acc[pr * 4 + 3][r];
                float cn = fast_sigmoid(fv) * cst[pr * 4 + r] + fast_sigmoid(iv) * fast_tanh(gv);
                cst[pr * 4 + r] = cn;
                float hv = fast_sigmoid(ov) * fast_tanh(cn);
                Abuf[pn][akc * 4 + r][(2 * w + pr) * 16 + arow] = __float2bfloat16(hv);
            }
        }
        if (tid < 256) Abuf[pn][tid >> 4][256 + (tid & 15)] = __float2bfloat16(xv);
        __syncthreads();
    }

    // tail: out[2047] from h_2047 (sits in Abuf[0] after the last step)
    if (w == 7) {
        f32x4 accO = (f32x4){bs[8], bs[8], bs[8], bs[8]};
        bf16x8 aff[9];
        const __hip_bfloat16* ab2 = &Abuf[0][arow][akc * 8];
        #pragma unroll
        for (int kt = 0; kt < KSTEPS; ++kt)
            aff[kt] = *(const bf16x8*)(ab2 + kt * 32);
        #pragma unroll
        for (int kt = 0; kt < KSTEPS; ++kt) {
            bf16x8 wf = Wf[(64 * KSTEPS + kt) * 64 + lane];
            accO = __builtin_amdgcn_mfma_f32_16x16x32_bf16(aff[kt], wf, accO, 0, 0, 0);
        }
        int n = lane & 15;
        if (n < 6) {
            #pragma unroll
            for (int r = 0; r < 4; ++r) {
                int b = akc * 4 + r;
                out[(((size_t)(T_STEPS - 1) * BATCH) + bg * BBLK + b) * 6 + n] = accO[r];
            }
        }
    }
}

extern "C" void kernel_launch(void* const* d_in, const int* in_sizes, int n_in,
                              void* d_out, int out_size, void* d_ws, size_t ws_size,
                              hipStream_t stream) {
    const float* xs   = (const float*)d_in[0];
    const float* Wih  = (const float*)d_in[1];
    const float* Whh  = (const float*)d_in[2];
    const float* bih  = (const float*)d_in[3];
    const float* bhh  = (const float*)d_in[4];
    const float* Wuvw = (const float*)d_in[5];
    const float* buvw = (const float*)d_in[6];
    const float* Wpqr = (const float*)d_in[7];
    const float* bpqr = (const float*)d_in[8];
    float* out = (float*)d_out;

    __hip_bfloat16* Wp = (__hip_bfloat16*)d_ws;
    float* bias = (float*)((char*)d_ws + (size_t)NT_ALL * KSTEPS * 64 * 8 * sizeof(__hip_bfloat16));

    pack_kernel<<<(NT_ALL * KSTEPS * 64 * 8 + 255) / 256, 256, 0, stream>>>(
        Wih, Whh, bih, bhh, Wuvw, buvw, Wpqr, bpqr, Wp, bias);
    lstm_kernel<<<NBLK, 512, 0, stream>>>(xs, Wp, bias, out);
}

// Round 2
// 13078.383 us; speedup vs baseline: 1.8650x; 1.8650x over previous
//
#include <hip/hip_runtime.h>
#include <hip/hip_bf16.h>

#define T_STEPS 2048
#define BATCH   256
#define DIN     16
#define HIDDEN  256
#define KROW    296      // padded A row stride (bf16 elems): 256 h + 16 x + 16 zero + 8 pad
#define NT_ALL  65       // 64 gate tiles + 1 output tile
#define KSTEPS  9        // K = 288 = 9 * 32
#define BBLK    16       // batch rows per block
#define NTHREADS 320     // 5 waves: 4 compute + 1 aux (x prefetch / out tile)

// workspace layout (bytes)
#define WP_ELEMS   (NT_ALL * KSTEPS * 64 * 8)          // bf16 elems = 299520
#define BIAS_OFF   ((size_t)WP_ELEMS * 2)              // 599040
#define HX_OFF     (BIAS_OFF + NT_ALL * 16 * 4)        // 603200 (8B aligned)
#define HX_BYTES   ((size_t)2 * 16 * 4 * 256 * 8)      // 262144
#define FLAGS_OFF  (HX_OFF + HX_BYTES)                 // 865344
#define FLAGS_BYTES ((size_t)16 * 4 * 4 * 4)           // 1024

typedef __attribute__((ext_vector_type(8))) short bf16x8;
typedef __attribute__((ext_vector_type(4))) float f32x4;

__device__ __forceinline__ float fast_sigmoid(float x) {
    return __builtin_amdgcn_rcpf(1.f + __expf(-x));
}
__device__ __forceinline__ float fast_tanh(float x) {
    return 1.f - 2.f * __builtin_amdgcn_rcpf(1.f + __expf(2.f * x));
}
__device__ __forceinline__ unsigned short bf16b(float v) {
    return __bfloat16_as_ushort(__float2bfloat16(v));
}

// Pack W into MFMA-B fragment order (unchanged from round 1):
// Wp[((tt*9+kt)*64+lane)*8+e]; tile tt<64: gate=tt&3, jt=tt>>2, col n=lane&15
// -> gate row g = gate*256 + jt*16 + n; k: [0,256)=W_hh, [256,272)=W_ih, rest 0.
// tile 64: cols 0..2 = W_uvw rows, 3..5 = W_pqr rows, x-cols zero.
__global__ void pack_kernel(const float* __restrict__ W_ih, const float* __restrict__ W_hh,
                            const float* __restrict__ b_ih, const float* __restrict__ b_hh,
                            const float* __restrict__ W_uvw, const float* __restrict__ b_uvw,
                            const float* __restrict__ W_pqr, const float* __restrict__ b_pqr,
                            __hip_bfloat16* __restrict__ Wp, float* __restrict__ bias) {
    int idx = blockIdx.x * 256 + threadIdx.x;
    if (idx < WP_ELEMS) {
        int e   = idx & 7;
        int L   = (idx >> 3) & 63;
        int rem = idx >> 9;
        int kt  = rem % KSTEPS;
        int tt  = rem / KSTEPS;
        int n   = L & 15;
        int k   = kt * 32 + (L >> 4) * 8 + e;
        float v = 0.f;
        if (tt < 64) {
            int gr = (tt & 3) * 256 + (tt >> 2) * 16 + n;
            if (k < 256)       v = W_hh[gr * 256 + k];
            else if (k < 272)  v = W_ih[gr * 16 + (k - 256)];
        } else if (k < 256) {
            if (n < 3)      v = W_uvw[n * 256 + k];
            else if (n < 6) v = W_pqr[(n - 3) * 256 + k];
        }
        Wp[idx] = __float2bfloat16(v);
    }
    if (idx < NT_ALL * 16) {
        int tt = idx >> 4, n = idx & 15;
        float bv = 0.f;
        if (tt < 64) {
            int gr = (tt & 3) * 256 + (tt >> 2) * 16 + n;
            bv = b_ih[gr] + b_hh[gr];
        } else {
            if (n < 3)      bv = b_uvw[n];
            else if (n < 6) bv = b_pqr[n - 3];
        }
        bias[idx] = bv;
    }
}

// 64 persistent blocks: q = blockIdx>>4 (hidden slice of 64 j), g = blockIdx&15
// (batch rows 16g..16g+16). Waves 0-3: wave w owns j-tile q*4+w, all 4 gates
// (tiles (q*4+w)*4 + 0..3) -> W fully register-resident (144 VGPR/lane), c in
// regs, lane-local activations. Wave 4: x prefetch; in q==0 also the out tile.
// Cross-block h exchange each step via packed-u64 agent atomics + seq flags.
__global__ __launch_bounds__(NTHREADS, 1) void lstm_kernel(
        const float* __restrict__ xs, const __hip_bfloat16* __restrict__ Wp,
        const float* __restrict__ bias, unsigned long long* __restrict__ Hx,
        unsigned int* __restrict__ flags, float* __restrict__ out) {
    __shared__ __hip_bfloat16 Abuf[2][BBLK][KROW];
    const int tid  = threadIdx.x;
    const int w    = tid >> 6;        // 0..4
    const int lane = tid & 63;
    const int q    = blockIdx.x >> 4; // hidden slice 0..3
    const int g    = blockIdx.x & 15; // batch group 0..15
    const int arow = lane & 15;       // tile col (j low bits / out col)
    const int akc  = lane >> 4;       // 0..3

    // zero both A panels (h_{-1}=0, zero-pad K cols)
    for (int i = tid; i < 2 * BBLK * KROW; i += NTHREADS)
        ((__hip_bfloat16*)Abuf)[i] = __ushort_as_bfloat16(0);
    __syncthreads();

    // stage x_0 into panel 0 (wave 4; thread: b=lane>>2, 4-float chunk ch=lane&3)
    if (w == 4) {
        int b = lane >> 2, ch = lane & 3;
        const float4 xv = *(const float4*)&xs[((size_t)0 * BATCH + g * BBLK + b) * DIN + (ch << 2)];
        unsigned int p0 = ((unsigned)bf16b(xv.y) << 16) | bf16b(xv.x);
        unsigned int p1 = ((unsigned)bf16b(xv.w) << 16) | bf16b(xv.z);
        *(uint2*)&Abuf[0][b][256 + (ch << 2)] = make_uint2(p0, p1);
    }

    // persistent W fragments (loaded once)
    const bf16x8* Wf = (const bf16x8*)Wp;
    bf16x8 wfr[4][9];
    float bs[4] = {0.f, 0.f, 0.f, 0.f};
    if (w < 4) {
        int jt = q * 4 + w;
        #pragma unroll
        for (int gi = 0; gi < 4; ++gi) {
            #pragma unroll
            for (int kt = 0; kt < KSTEPS; ++kt)
                wfr[gi][kt] = Wf[(((jt << 2) + gi) * KSTEPS + kt) * 64 + lane];
            bs[gi] = bias[((jt << 2) + gi) * 16 + arow];
        }
    }
    bf16x8 wout[9];
    float bo = 0.f;
    if (w == 4 && q == 0) {
        #pragma unroll
        for (int kt = 0; kt < KSTEPS; ++kt) wout[kt] = Wf[(64 * KSTEPS + kt) * 64 + lane];
        bo = bias[64 * 16 + arow];
    }

    float cst[4] = {0.f, 0.f, 0.f, 0.f};

    for (int t = 0; t <= T_STEPS; ++t) {
        const int p  = t & 1;
        const int pn = p ^ 1;

        // ---- wait for remote h_{t-1} (12 spinners: 3 remote q x 4 waves)
        if (tid < 12) {
            int qq = tid >> 2;
            int qr = qq + (qq >= q ? 1 : 0);
            const unsigned int* fp = &flags[(((g << 2) + qr) << 2) + (tid & 3)];
            while (__hip_atomic_load(fp, __ATOMIC_ACQUIRE, __HIP_MEMORY_SCOPE_AGENT) < (unsigned)t) {}
        }
        __syncthreads();  // B1

        // ---- gather remote h_{t-1} (slot pn) into panel[p]
        {
            const unsigned long long* HS = Hx + (((size_t)pn * 16 + g) << 10);
            for (int f = tid; f < 768; f += NTHREADS) {
                int qq = f >> 8;
                int qr = qq + (qq >= q ? 1 : 0);
                int r  = f & 255;
                unsigned long long v =
                    __hip_atomic_load(&HS[(qr << 8) + r], __ATOMIC_RELAXED, __HIP_MEMORY_SCOPE_AGENT);
                int col = (qr << 6) + (r >> 2);
                int bb  = (r & 3) << 2;
                Abuf[p][bb + 0][col] = __ushort_as_bfloat16((unsigned short)(v));
                Abuf[p][bb + 1][col] = __ushort_as_bfloat16((unsigned short)(v >> 16));
                Abuf[p][bb + 2][col] = __ushort_as_bfloat16((unsigned short)(v >> 32));
                Abuf[p][bb + 3][col] = __ushort_as_bfloat16((unsigned short)(v >> 48));
            }
        }
        __syncthreads();  // B2

        // ---- gates + recurrence (waves 0-3)
        if (w < 4 && t < T_STEPS) {
            bf16x8 af[9];
            const __hip_bfloat16* ab = &Abuf[p][arow][akc * 8];
            #pragma unroll
            for (int kt = 0; kt < KSTEPS; ++kt) af[kt] = *(const bf16x8*)(ab + kt * 32);
            f32x4 acc[4];
            #pragma unroll
            for (int gi = 0; gi < 4; ++gi) acc[gi] = (f32x4){bs[gi], bs[gi], bs[gi], bs[gi]};
            #pragma unroll
            for (int kt = 0; kt < KSTEPS; ++kt)
                #pragma unroll
                for (int gi = 0; gi < 4; ++gi)
                    acc[gi] = __builtin_amdgcn_mfma_f32_16x16x32_bf16(af[kt], wfr[gi][kt], acc[gi], 0, 0, 0);

            // lane-local activations; c persistent in regs
            unsigned long long hv64 = 0;
            #pragma unroll
            for (int r = 0; r < 4; ++r) {
                float iv = acc[0][r], fv = acc[1][r], gv = acc[2][r], ov = acc[3][r];
                float cn = fast_sigmoid(fv) * cst[r] + fast_sigmoid(iv) * fast_tanh(gv);
                cst[r] = cn;
                float hvf = fast_sigmoid(ov) * fast_tanh(cn);
                unsigned short hb = bf16b(hvf);
                Abuf[pn][(akc << 2) + r][(q << 6) + (w << 4) + arow] = __ushort_as_bfloat16(hb);
                hv64 |= (unsigned long long)hb << (16 * r);
            }
            // publish own slice of h_t (slot p) + per-wave flag
            unsigned long long* HD = Hx + (((size_t)p * 16 + g) << 10) + (q << 8)
                                     + (((w << 4) + arow) << 2) + akc;
            __hip_atomic_store(HD, hv64, __ATOMIC_RELAXED, __HIP_MEMORY_SCOPE_AGENT);
            __threadfence();   // wave-wide vmcnt drain orders the whole wave's stores
            if (lane == 0)
                __hip_atomic_store(&flags[(((g << 2) + q) << 2) + w], (unsigned)(t + 1),
                                   __ATOMIC_RELAXED, __HIP_MEMORY_SCOPE_AGENT);
        }

        // ---- out tile: out[t-1] from assembled h_{t-1} (wave 4 of q==0)
        if (w == 4 && q == 0 && t >= 1) {
            bf16x8 af[9];
            const __hip_bfloat16* ab = &Abuf[p][arow][akc * 8];
            #pragma unroll
            for (int kt = 0; kt < KSTEPS; ++kt) af[kt] = *(const bf16x8*)(ab + kt * 32);
            f32x4 accO = (f32x4){bo, bo, bo, bo};
            #pragma unroll
            for (int kt = 0; kt < KSTEPS; ++kt)
                accO = __builtin_amdgcn_mfma_f32_16x16x32_bf16(af[kt], wout[kt], accO, 0, 0, 0);
            if (arow < 6) {
                #pragma unroll
                for (int r = 0; r < 4; ++r)
                    out[(((size_t)(t - 1) * BATCH) + g * BBLK + (akc << 2) + r) * 6 + arow] = accO[r];
            }
        }

        // ---- prefetch x_{t+1} into panel[pn] (wave 4, all blocks)
        if (w == 4 && t + 1 < T_STEPS) {
            int b = lane >> 2, ch = lane & 3;
            const float4 xv = *(const float4*)&xs[((size_t)(t + 1) * BATCH + g * BBLK + b) * DIN + (ch << 2)];
            unsigned int p0 = ((unsigned)bf16b(xv.y) << 16) | bf16b(xv.x);
            unsigned int p1 = ((unsigned)bf16b(xv.w) << 16) | bf16b(xv.z);
            *(uint2*)&Abuf[pn][b][256 + (ch << 2)] = make_uint2(p0, p1);
        }
    }
}

extern "C" void kernel_launch(void* const* d_in, const int* in_sizes, int n_in,
                              void* d_out, int out_size, void* d_ws, size_t ws_size,
                              hipStream_t stream) {
    const float* xs   = (const float*)d_in[0];
    const float* Wih  = (const float*)d_in[1];
    const float* Whh  = (const float*)d_in[2];
    const float* bih  = (const float*)d_in[3];
    const float* bhh  = (const float*)d_in[4];
    const float* Wuvw = (const float*)d_in[5];
    const float* buvw = (const float*)d_in[6];
    const float* Wpqr = (const float*)d_in[7];
    const float* bpqr = (const float*)d_in[8];
    float* out = (float*)d_out;

    __hip_bfloat16* Wp = (__hip_bfloat16*)d_ws;
    float* bias = (float*)((char*)d_ws + BIAS_OFF);
    unsigned long long* Hx = (unsigned long long*)((char*)d_ws + HX_OFF);
    unsigned int* flags = (unsigned int*)((char*)d_ws + FLAGS_OFF);

    // flags must start at 0 and exchange slot 1 must read as h=0 for t=0
    hipMemsetAsync(Hx, 0, HX_BYTES, stream);
    hipMemsetAsync(flags, 0, FLAGS_BYTES, stream);

    pack_kernel<<<(WP_ELEMS + 255) / 256, 256, 0, stream>>>(
        Wih, Whh, bih, bhh, Wuvw, buvw, Wpqr, bpqr, Wp, bias);
    lstm_kernel<<<64, NTHREADS, 0, stream>>>(xs, Wp, bias, Hx, flags, out);
}

// Round 3
// 5227.505 us; speedup vs baseline: 4.6660x; 2.5018x over previous
//
#include <hip/hip_runtime.h>
#include <hip/hip_bf16.h>

#define T_STEPS 2048
#define BATCH   256
#define DIN     16
#define KROW    296      // padded A row stride (bf16): 256 h + 16 x + 16 zero + 8 pad
#define NT_ALL  65       // 64 gate tiles + 1 output tile
#define KSTEPS  9        // K = 288 = 9 * 32
#define BBLK    16       // batch rows per block
#define NTHREADS 320     // 5 waves: 4 compute + 1 aux
#define GWORDS  1536     // remote words to gather: 3 slices * 512
#define SLOT_STRIDE 32768 // u64 per slot: 16 g * 4 q * 512

#define WP_ELEMS (NT_ALL * KSTEPS * 64 * 8)
#define BIAS_OFF ((size_t)WP_ELEMS * 2)                 // 599040
#define HX_OFF   (BIAS_OFF + (size_t)NT_ALL * 16 * 4)   // 603200 (8B aligned)
#define HX_BYTES ((size_t)2 * SLOT_STRIDE * 8)          // 524288

typedef __attribute__((ext_vector_type(8))) short bf16x8;
typedef __attribute__((ext_vector_type(4))) float f32x4;

__device__ __forceinline__ float fast_sigmoid(float x) {
    return __builtin_amdgcn_rcpf(1.f + __expf(-x));
}
__device__ __forceinline__ float fast_tanh(float x) {
    return 1.f - 2.f * __builtin_amdgcn_rcpf(1.f + __expf(2.f * x));
}
__device__ __forceinline__ unsigned short bf16b(float v) {
    return __bfloat16_as_ushort(__float2bfloat16(v));
}

// Pack W into MFMA-B fragment order (identical to round 2, verified).
__global__ void pack_kernel(const float* __restrict__ W_ih, const float* __restrict__ W_hh,
                            const float* __restrict__ b_ih, const float* __restrict__ b_hh,
                            const float* __restrict__ W_uvw, const float* __restrict__ b_uvw,
                            const float* __restrict__ W_pqr, const float* __restrict__ b_pqr,
                            __hip_bfloat16* __restrict__ Wp, float* __restrict__ bias) {
    int idx = blockIdx.x * 256 + threadIdx.x;
    if (idx < WP_ELEMS) {
        int e   = idx & 7;
        int L   = (idx >> 3) & 63;
        int rem = idx >> 9;
        int kt  = rem % KSTEPS;
        int tt  = rem / KSTEPS;
        int n   = L & 15;
        int k   = kt * 32 + (L >> 4) * 8 + e;
        float v = 0.f;
        if (tt < 64) {
            int gr = (tt & 3) * 256 + (tt >> 2) * 16 + n;
            if (k < 256)       v = W_hh[gr * 256 + k];
            else if (k < 272)  v = W_ih[gr * 16 + (k - 256)];
        } else if (k < 256) {
            if (n < 3)      v = W_uvw[n * 256 + k];
            else if (n < 6) v = W_pqr[(n - 3) * 256 + k];
        }
        Wp[idx] = __float2bfloat16(v);
    }
    if (idx < NT_ALL * 16) {
        int tt = idx >> 4, n = idx & 15;
        float bv = 0.f;
        if (tt < 64) {
            int gr = (tt & 3) * 256 + (tt >> 2) * 16 + n;
            bv = b_ih[gr] + b_hh[gr];
        } else {
            if (n < 3)      bv = b_uvw[n];
            else if (n < 6) bv = b_pqr[n - 3];
        }
        bias[idx] = bv;
    }
}

// 64 persistent blocks: q = bIdx>>4 (64-j slice), g = bIdx&15 (16 batch rows).
// Exchange protocol: self-validating words. u64 = {hi32 = tag, lo32 = 2 bf16}.
// Writer at iter t stores tag t+1 into slot t&1 (2 relaxed agent u64 stores,
// no fence, no flag). Reader at iter t polls slot (t+1)&1 for tag == t and
// scatters matched words straight into the LDS A-panel. One barrier per step.
__global__ __launch_bounds__(NTHREADS, 1) void lstm_kernel(
        const float* __restrict__ xs, const __hip_bfloat16* __restrict__ Wp,
        const float* __restrict__ bias, unsigned long long* __restrict__ Hx,
        float* __restrict__ out) {
    __shared__ __hip_bfloat16 Abuf[2][BBLK][KROW];
    const int tid  = threadIdx.x;
    const int w    = tid >> 6;        // 0..4
    const int lane = tid & 63;
    const int q    = blockIdx.x >> 4; // hidden slice 0..3
    const int g    = blockIdx.x & 15; // batch group 0..15
    const int arow = lane & 15;
    const int akc  = lane >> 4;

    // zero both A panels
    for (int i = tid; i < 2 * BBLK * KROW; i += NTHREADS)
        ((__hip_bfloat16*)Abuf)[i] = __ushort_as_bfloat16(0);
    __syncthreads();

    // stage x_0 into panel 0
    if (w == 4) {
        int b = lane >> 2, ch = lane & 3;
        const float4 xv = *(const float4*)&xs[((size_t)0 * BATCH + g * BBLK + b) * DIN + (ch << 2)];
        unsigned int p0 = ((unsigned)bf16b(xv.y) << 16) | bf16b(xv.x);
        unsigned int p1 = ((unsigned)bf16b(xv.w) << 16) | bf16b(xv.z);
        *(uint2*)&Abuf[0][b][256 + (ch << 2)] = make_uint2(p0, p1);
    }

    // persistent W fragments (loaded once; read-only across the t-loop)
    const bf16x8* Wf = (const bf16x8*)Wp;
    bf16x8 wfr[4][9];
    float bs[4] = {0.f, 0.f, 0.f, 0.f};
    if (w < 4) {
        int jt = q * 4 + w;
        #pragma unroll
        for (int gi = 0; gi < 4; ++gi) {
            #pragma unroll
            for (int kt = 0; kt < KSTEPS; ++kt)
                wfr[gi][kt] = Wf[(((jt << 2) + gi) * KSTEPS + kt) * 64 + lane];
            bs[gi] = bias[((jt << 2) + gi) * 16 + arow];
        }
    }
    bf16x8 wout[9];
    float bo = 0.f;
    if (w == 4 && q == 0) {
        #pragma unroll
        for (int kt = 0; kt < KSTEPS; ++kt) wout[kt] = Wf[(64 * KSTEPS + kt) * 64 + lane];
        bo = bias[64 * 16 + arow];
    }

    // per-thread gather list (step-invariant): word offsets + LDS targets
    int nw = 0;
    int wo[5], lcol[5], lb0[5];
    #pragma unroll
    for (int k = 0; k < 5; ++k) {
        int f = tid + k * NTHREADS;
        if (f < GWORDS) {
            int qq = f >> 9;
            int qr = qq + (qq >= q ? 1 : 0);
            int r  = f & 511;
            int wr = r >> 7;
            int pr = (r >> 6) & 1;
            int lr = r & 63;
            wo[nw]   = ((g << 2) + qr) * 512 + r;
            lcol[nw] = (qr << 6) + (wr << 4) + (lr & 15);
            lb0[nw]  = ((lr >> 4) << 2) + (pr << 1);
            ++nw;
        }
    }
    const unsigned fullmask = (nw == 5) ? 31u : 15u;

    // writer base: pair0 word index = w*128 + lane (pair-major, coalesced)
    unsigned long long* HWbase = Hx + ((g << 2) + q) * 512 + (w << 7) + lane;

    float cst[4] = {0.f, 0.f, 0.f, 0.f};

    for (int t = 0; t <= T_STEPS; ++t) {
        const int p  = t & 1;
        const int pn = p ^ 1;

        // issue x_{t+1} load early (wave 4), landing in regs during the poll
        float4 xv;
        if (w == 4 && t + 1 < T_STEPS) {
            int b = lane >> 2, ch = lane & 3;
            xv = *(const float4*)&xs[((size_t)(t + 1) * BATCH + g * BBLK + b) * DIN + (ch << 2)];
        }

        // ---- poll remote words (tag == t in slot (t+1)&1), scatter to LDS[p]
        {
            const unsigned long long* HS = Hx + (size_t)((t + 1) & 1) * SLOT_STRIDE;
            const unsigned tagw = (unsigned)t;
            unsigned valid = 0;
            while (valid != fullmask) {
                #pragma unroll
                for (int k = 0; k < 5; ++k) {
                    if (k < nw && !(valid & (1u << k))) {
                        unsigned long long v = __hip_atomic_load(
                            &HS[wo[k]], __ATOMIC_RELAXED, __HIP_MEMORY_SCOPE_AGENT);
                        if ((unsigned)(v >> 32) == tagw) {
                            unsigned lo = (unsigned)v;
                            Abuf[p][lb0[k]][lcol[k]]     = __ushort_as_bfloat16((unsigned short)lo);
                            Abuf[p][lb0[k] + 1][lcol[k]] = __ushort_as_bfloat16((unsigned short)(lo >> 16));
                            valid |= (1u << k);
                        }
                    }
                }
            }
        }
        __syncthreads();

        // ---- gates + recurrence (waves 0-3)
        if (w < 4 && t < T_STEPS) {
            f32x4 acc[4];
            #pragma unroll
            for (int gi = 0; gi < 4; ++gi) acc[gi] = (f32x4){bs[gi], bs[gi], bs[gi], bs[gi]};
            const __hip_bfloat16* ab = &Abuf[p][arow][akc * 8];
            #pragma unroll
            for (int kt = 0; kt < KSTEPS; ++kt) {
                bf16x8 a = *(const bf16x8*)(ab + kt * 32);
                #pragma unroll
                for (int gi = 0; gi < 4; ++gi)
                    acc[gi] = __builtin_amdgcn_mfma_f32_16x16x32_bf16(a, wfr[gi][kt], acc[gi], 0, 0, 0);
            }

            // lane-local activations; c persistent in regs
            unsigned hp[2];
            unsigned short hb[4];
            #pragma unroll
            for (int r = 0; r < 4; ++r) {
                float iv = acc[0][r], fv = acc[1][r], gv = acc[2][r], ov = acc[3][r];
                float cn = fast_sigmoid(fv) * cst[r] + fast_sigmoid(iv) * fast_tanh(gv);
                cst[r] = cn;
                hb[r] = bf16b(fast_sigmoid(ov) * fast_tanh(cn));
            }
            hp[0] = ((unsigned)hb[1] << 16) | hb[0];
            hp[1] = ((unsigned)hb[3] << 16) | hb[2];

            // publish immediately (fire-and-forget, tag makes it self-validating)
            unsigned long long tg = ((unsigned long long)(unsigned)(t + 1)) << 32;
            unsigned long long* HD = HWbase + (size_t)(t & 1) * SLOT_STRIDE;
            __hip_atomic_store(HD,      tg | hp[0], __ATOMIC_RELAXED, __HIP_MEMORY_SCOPE_AGENT);
            __hip_atomic_store(HD + 64, tg | hp[1], __ATOMIC_RELAXED, __HIP_MEMORY_SCOPE_AGENT);

            // own slice into next panel
            int col = (q << 6) + (w << 4) + arow;
            #pragma unroll
            for (int r = 0; r < 4; ++r)
                Abuf[pn][(akc << 2) + r][col] = __ushort_as_bfloat16(hb[r]);
        }

        // ---- out tile: out[t-1] from assembled h_{t-1} (wave 4 of q==0)
        if (w == 4 && q == 0 && t >= 1) {
            f32x4 accO = (f32x4){bo, bo, bo, bo};
            const __hip_bfloat16* ab = &Abuf[p][arow][akc * 8];
            #pragma unroll
            for (int kt = 0; kt < KSTEPS; ++kt) {
                bf16x8 a = *(const bf16x8*)(ab + kt * 32);
                accO = __builtin_amdgcn_mfma_f32_16x16x32_bf16(a, wout[kt], accO, 0, 0, 0);
            }
            if (arow < 6) {
                #pragma unroll
                for (int r = 0; r < 4; ++r)
                    out[(((size_t)(t - 1) * BATCH) + g * BBLK + (akc << 2) + r) * 6 + arow] = accO[r];
            }
        }

        // ---- stage x_{t+1} into panel pn (wave 4)
        if (w == 4 && t + 1 < T_STEPS) {
            int b = lane >> 2, ch = lane & 3;
            unsigned int p0 = ((unsigned)bf16b(xv.y) << 16) | bf16b(xv.x);
            unsigned int p1 = ((unsigned)bf16b(xv.w) << 16) | bf16b(xv.z);
            *(uint2*)&Abuf[pn][b][256 + (ch << 2)] = make_uint2(p0, p1);
        }
    }
}

extern "C" void kernel_launch(void* const* d_in, const int* in_sizes, int n_in,
                              void* d_out, int out_size, void* d_ws, size_t ws_size,
                              hipStream_t stream) {
    const float* xs   = (const float*)d_in[0];
    const float* Wih  = (const float*)d_in[1];
    const float* Whh  = (const float*)d_in[2];
    const float* bih  = (const float*)d_in[3];
    const float* bhh  = (const float*)d_in[4];
    const float* Wuvw = (const float*)d_in[5];
    const float* buvw = (const float*)d_in[6];
    const float* Wpqr = (const float*)d_in[7];
    const float* bpqr = (const float*)d_in[8];
    float* out = (float*)d_out;

    __hip_bfloat16* Wp = (__hip_bfloat16*)d_ws;
    float* bias = (float*)((char*)d_ws + BIAS_OFF);
    unsigned long long* Hx = (unsigned long long*)((char*)d_ws + HX_OFF);

    // tags must start at 0 (t=0 reads slot 1 expecting tag 0 with h=0 data)
    hipMemsetAsync(Hx, 0, HX_BYTES, stream);

    pack_kernel<<<(WP_ELEMS + 255) / 256, 256, 0, stream>>>(
        Wih, Whh, bih, bhh, Wuvw, buvw, Wpqr, bpqr, Wp, bias);
    lstm_kernel<<<64, NTHREADS, 0, stream>>>(xs, Wp, bias, Hx, out);
}